// Round 5
// baseline (170.832 us; speedup 1.0000x reference)
//
#include <hip/hip_runtime.h>

// SMPL body model forward.
// R18: overlap + occupancy round.
//  (1) k_static's pre section (SJ/JT, the only thing k_head depends on)
//      split into tiny k_pre (72 blocks). k_head re-expressed as 4 waves x
//      4 n per 256-thread block and MERGED into k_prep with the remaining
//      static sections (head blocks first): head's serial-FK latency now
//      hides under regbf/bt/wt bandwidth work instead of serializing.
//  (2) k_regm re-sliced 6 splits x 9 steps -> 9 splits x 6 steps:
//      864 blocks = 13.5 waves/CU (was 9) for +50% latency hiding;
//      atomics 875K -> 1.31M (~+1-2us, net win expected).
//  (3) regbf compacted 8 elem/thread (2592 -> 324 blocks); each thread's
//      8 v-consecutive values are exactly one contiguous 16B fragment store.
// Fixed overhead in the timed region: 2x ~43us harness ws-poison fills.

constexpr int N   = 512;
constexpr int V   = 6890;
constexpr int V3  = V * 3;        // 20670
constexpr int NJ  = 24;
constexpr int NB  = 10;
constexpr int NP  = 207;
constexpr int NK  = 95;
constexpr int KP  = 224;          // padded K for pose GEMM
constexpr int VP2 = 6912;         // V padded (108*64)

// workspace layout (float offsets)
constexpr size_t SCALE_OFF = (size_t)N * V3;                  // N
constexpr size_t SJ_OFF    = SCALE_OFF + N;                   // NB*72
constexpr size_t JT_OFF    = SJ_OFF + (size_t)NB * 72;        // 72
constexpr size_t J_OFF     = JT_OFF + 72;
constexpr size_t A_OFF     = J_OFF + (size_t)N * 72;
constexpr size_t BF_OFF    = A_OFF + (size_t)N * 288;         // bf16/fp16 region
// region (ushort offsets)
constexpr size_t APF_U     = 0;                               // apf_sw [N/16][7][64][8] bf16
constexpr int    BP_COLS   = 20736;                           // 108*192 col pad
constexpr size_t BP_U      = (size_t)N * KP;                  // bp_sw [1296][7][64][8] bf16
constexpr size_t RB_U      = BP_U + (size_t)BP_COLS * KP;     // reg fp16 frag [6][216][64][8]
constexpr size_t VB_U      = RB_U + (size_t)96 * VP2;         // verts fp16 [N][3][VP2]
constexpr size_t BF_END_U  = VB_U + (size_t)N * 3 * VP2;
constexpr size_t WT_OFF    = BF_OFF + (BF_END_U + 1) / 2;     // w16 fp16 [VP2][32]
constexpr size_t AN_OFF    = WT_OFF + (size_t)VP2 * 32 / 2;   // an16 fp16 [N][16][32]

// k_prep section block counts (head | regbf | bt | wt)
constexpr int NB_HEAD  = N / 4;              // 128
constexpr int NB_REGBF = (96 * VP2) / (256 * 8);  // 324
constexpr int NB_BT    = BP_COLS / 64;       // 324
constexpr int NB_WT    = VP2 / 256;          // 27
constexpr int NB_PREP  = NB_HEAD + NB_REGBF + NB_BT + NB_WT;

typedef short s16x8 __attribute__((ext_vector_type(8)));
typedef _Float16 h16x8 __attribute__((ext_vector_type(8)));
typedef _Float16 h16x4 __attribute__((ext_vector_type(4)));
typedef float f32x4 __attribute__((ext_vector_type(4)));

__device__ inline unsigned short f2bf(float f) {
    unsigned u = __float_as_uint(f);
    u += 0x7fffu + ((u >> 16) & 1u);   // round-to-nearest-even
    return (unsigned short)(u >> 16);
}

// ---------------------------------------------------------------------------
// k_pre: SJ / Jt (the only k_head dependency). Block per jc, shuffle reduce.
__global__ __launch_bounds__(256) void k_pre(const float* __restrict__ jreg,
                                             const float* __restrict__ sd,
                                             const float* __restrict__ vt,
                                             float* __restrict__ ws) {
    int jc = blockIdx.x;                 // 0..71
    int tid = threadIdx.x;
    int j = jc / 3, c = jc % 3;
    float acc[NB + 1];
#pragma unroll
    for (int t = 0; t <= NB; ++t) acc[t] = 0.f;
    for (int v = tid; v < V; v += 256) {
        float w = jreg[(size_t)j * V + v];
        int col = v * 3 + c;
#pragma unroll
        for (int k = 0; k < NB; ++k) acc[k] += w * sd[(size_t)k * V3 + col];
        acc[NB] += w * vt[col];
    }
    __shared__ float red[64];
    int lane = tid & 63, w64 = tid >> 6;
#pragma unroll
    for (int t = 0; t <= NB; ++t) {
        float a = acc[t];
#pragma unroll
        for (int s = 1; s < 64; s <<= 1) a += __shfl_xor(a, s, 64);
        if (lane == 0) red[w64 * 16 + t] = a;
    }
    __syncthreads();
    if (tid <= NB) {
        float s = red[tid] + red[16 + tid] + red[32 + tid] + red[48 + tid];
        if (tid < NB) ws[SJ_OFF + (size_t)tid * 72 + jc] = s;
        else          ws[JT_OFF + jc] = s;
    }
}

// ---------------------------------------------------------------------------
// k_prep: head (4 n per block, 1 wave each) | regbf | bt | wt.
__global__ __launch_bounds__(256) void k_prep(const float* __restrict__ pdirs,
                                              const float* __restrict__ sd,
                                              const float* __restrict__ vt,
                                              const float* __restrict__ lbsw,
                                              const float* __restrict__ b25,
                                              const float* __restrict__ face,
                                              const float* __restrict__ pose,
                                              const float* __restrict__ betas,
                                              unsigned short* __restrict__ bp,
                                              _Float16* __restrict__ rb,
                                              _Float16* __restrict__ w16,
                                              unsigned short* __restrict__ apf,
                                              _Float16* __restrict__ an16,
                                              float* __restrict__ ws) {
    __shared__ __align__(16) unsigned char smbuf[KP * 66 * 2];   // 29.6 KB shared pool
    int b = blockIdx.x;
    int tid = threadIdx.x;

    if (b < NB_HEAD) {
        // ---- head: wave w handles n = b*4+w. Per-wave LDS carved from pool.
        int w = tid >> 6, ln = tid & 63;
        int n = b * 4 + w;
        float* fbase = reinterpret_cast<float*>(smbuf);
        float* sval = fbase + w * 4;                       // [4][4]
        float* Jl   = fbase + 16 + w * 72;                 // [4][72]
        float* G    = fbase + 304 + w * 288;               // [4][288]
        unsigned short* pfsh =
            reinterpret_cast<unsigned short*>(fbase + 1456) + w * KP;  // [4][224]

        const int idx4[4] = {2802 * 3 + 1, 6262 * 3 + 1, 2237 * 3 + 1, 6728 * 3 + 1};
        if (ln < 4) {
            float a = vt[idx4[ln]];
#pragma unroll
            for (int k = 0; k < NB; ++k)
                a += betas[n * NB + k] * sd[(size_t)k * V3 + idx4[ln]];
            sval[ln] = a;
        }
        __syncthreads();
        float scale = 1.66f / (sval[0] + sval[1] - sval[2] - sval[3]);
        if (ln == 0) ws[SCALE_OFF + n] = scale;

        for (int k = ln; k < KP; k += 64) {
            float v = 0.f;
            if (k < NP) {
                v = pose[(size_t)n * 216 + 9 + k];
                int km = k % 9;
                if (km == 0 || km == 4 || km == 8) v -= 1.f;
            } else if (k < NP + NB) {
                v = scale * betas[n * NB + (k - NP)];
            }
            pfsh[k] = f2bf(v);
        }
        for (int e = ln; e < 72; e += 64) {
            float a = ws[JT_OFF + e];
#pragma unroll
            for (int k = 0; k < NB; ++k)
                a += betas[n * NB + k] * ws[SJ_OFF + (size_t)k * 72 + e];
            Jl[e] = scale * a;
        }
        __syncthreads();
        // apf fragment layout: [(n/16)*7+kk][lane=q*16+(n&15)][8]
        if (ln < 28) {
            int kk = ln >> 2, q = ln & 3;
            s16x8 r;
#pragma unroll
            for (int j = 0; j < 8; ++j) r[j] = (short)pfsh[kk * 32 + q * 8 + j];
            size_t off = ((size_t)(n >> 4) * 7 + kk) * 64 + q * 16 + (n & 15);
            *reinterpret_cast<s16x8*>(&apf[off * 8]) = r;
        }

        const int par[NJ] = {0,0,0,0,1,2,3,4,5,6,7,8,9,9,9,12,13,14,16,17,18,19,20,21};
        if (ln < 12) {
            int r = ln >> 2, c = ln & 3;
            G[ln] = (c < 3) ? pose[(size_t)n * 216 + r * 3 + c] : Jl[r];
        }
        __syncthreads();
        for (int i = 1; i < NJ; ++i) {
            int p = par[i];
            if (ln < 12) {
                int r = ln >> 2, c = ln & 3;
                const float* gp = &G[p * 12 + r * 4];
                float v;
                if (c < 3) {
                    const float* Ri = pose + (size_t)n * 216 + i * 9;
                    v = gp[0] * Ri[0 * 3 + c] + gp[1] * Ri[1 * 3 + c] + gp[2] * Ri[2 * 3 + c];
                } else {
                    float t0 = Jl[i * 3 + 0] - Jl[p * 3 + 0];
                    float t1 = Jl[i * 3 + 1] - Jl[p * 3 + 1];
                    float t2 = Jl[i * 3 + 2] - Jl[p * 3 + 2];
                    v = gp[0] * t0 + gp[1] * t1 + gp[2] * t2 + gp[3];
                }
                G[i * 12 + ln] = v;
            }
            __syncthreads();
        }
        // an16[n][col(16)][k=j(32)]
        for (int e = ln; e < 512; e += 64) {
            int col = e >> 5, j = e & 31;
            float v = 0.f;
            if (col < 12 && j < NJ) {
                int r = col >> 2, c = col & 3;
                if (c < 3) v = G[j * 12 + r * 4 + c];
                else {
                    const float* g = &G[j * 12 + r * 4];
                    v = g[3] - (g[0] * Jl[j * 3 + 0] + g[1] * Jl[j * 3 + 1]
                              + g[2] * Jl[j * 3 + 2]);
                }
            }
            an16[(size_t)n * 512 + e] = (_Float16)v;
        }
        return;
    }
    b -= NB_HEAD;
    if (b < NB_REGBF) {
        // rb in MFMA A-fragment layout for k_regm; 8 v-consecutive elements
        // per thread == one contiguous 16B fragment store.
        int t0 = (b * 256 + tid) * 8;
        int k = t0 / VP2, v = t0 - k * VP2;      // VP2%8==0 -> same k for all 8
        h16x8 val;
#pragma unroll
        for (int j = 0; j < 8; ++j) {
            float x = 0.f;
            int vv = v + j;
            if (vv < V && k < NK)
                x = (k < 25) ? b25[(size_t)k * V + vv] : face[(size_t)(k - 25) * V + vv];
            val[j] = (_Float16)x;
        }
        int kt = k >> 4, m16 = k & 15;
        int step = v >> 5, q8 = (v >> 3) & 3;
        *reinterpret_cast<h16x8*>(
            &rb[((size_t)(kt * 216 + step) * 64 + q8 * 16 + m16) * 8]) = val;
        return;
    }
    b -= NB_REGBF;
    if (b < NB_BT) {
        // stage [k][cl] (stride 66: conflict-free gather) then emit FRAGMENT
        // layout bp[(ctg*7+kk)*64+lane][8]
        unsigned short* smem = reinterpret_cast<unsigned short*>(smbuf);
        int c0 = b * 64;
#pragma unroll 4
        for (int i = 0; i < 56; ++i) {
            int e = tid + 256 * i;
            int k = e >> 6, cl = e & 63;
            int col = c0 + cl;
            float v = 0.f;
            if (col < V3) {
                if (k < NP) v = pdirs[(size_t)k * V3 + col];
                else if (k < NP + NB) v = sd[(size_t)(k - NP) * V3 + col];
            }
            smem[k * 66 + cl] = f2bf(v);
        }
        __syncthreads();
        for (int i = 0; i < 7; ++i) {
            int u = tid + 256 * i;                // 0..1791
            int ct_loc = u / 448;
            int rem = u - ct_loc * 448;
            int kk = rem >> 6, lane = rem & 63;
            int m = lane & 15, q = lane >> 4;
            s16x8 r;
#pragma unroll
            for (int j = 0; j < 8; ++j)
                r[j] = (short)smem[(kk * 32 + q * 8 + j) * 66 + ct_loc * 16 + m];
            size_t ctg = (size_t)(c0 >> 4) + ct_loc;
            *reinterpret_cast<s16x8*>(&bp[((ctg * 7 + kk) * 64 + lane) * 8]) = r;
        }
        return;
    }
    b -= NB_BT;
    // wt: w16[v][k=j] fp16, A-operand layout for the T-MFMA
    {
        float* t = reinterpret_cast<float*>(smbuf);
        int v0 = b * 256;
        for (int e = tid; e < 256 * 24; e += 256) {
            int g = v0 * 24 + e;
            float val = (g < V * NJ) ? lbsw[g] : 0.f;
            int vv = e / 24, j = e - vv * 24;
            t[vv * 25 + j] = val;
        }
        __syncthreads();
        _Float16* dst = w16 + (size_t)(v0 + tid) * 32;
#pragma unroll
        for (int j = 0; j < 32; ++j)
            dst[j] = (j < NJ) ? (_Float16)t[tid * 25 + j] : (_Float16)0.f;
    }
}

// ---------------------------------------------------------------------------
// k_gl: fused pose-GEMM + LBS, 32v x 32n tiles, grid (216,16). Wave w:
// wg=w&1 picks 16-n group, wc=w>>1 picks 48-col half (3 ct x 7 kk MFMAs).
// Stage 2: wave w owns 8 n-rows x 32 verts via 2 register w16 frags
// (operand-swapped T-MFMA: lane (m,q) gets T[q][0..3] of vertex g*16+m).
// 2 barriers total.
__global__ __launch_bounds__(256) void k_gl(const unsigned short* __restrict__ apf,
                                            const unsigned short* __restrict__ bp,
                                            const float* __restrict__ vt,
                                            const float* __restrict__ ws,
                                            const _Float16* __restrict__ w16,
                                            const _Float16* __restrict__ an16,
                                            const float* __restrict__ trans,
                                            _Float16* __restrict__ vb) {
    int tid = threadIdx.x;
    int lane = tid & 63, w = tid >> 6;
    int m = lane & 15, q = lane >> 4;
    int cb = blockIdx.x;                 // 0..215  (32-v tile)
    int nb = blockIdx.y;                 // 0..15   (32-n tile)
    int wg = w & 1;                      // n 16-group within tile
    int wc = w >> 1;                     // col 48-half

    // posed verts [n(32)][v(33 pad)][c(4)] fp16 = 8.25 KB; row stride 264 B.
    __shared__ __align__(16) _Float16 sm[32][33][4];
    __shared__ float svt[96];
    __shared__ float ssc[32];
    __shared__ float strans[96];
    if (tid < 96) {
        int col = cb * 96 + tid;
        svt[tid] = (col < V3) ? vt[col] : 0.f;
        strans[tid] = trans[nb * 96 + tid];
    }
    if (tid < 32) ssc[tid] = ws[SCALE_OFF + nb * 32 + tid];

    // ---- stage 1: pose GEMM (16 n x 48 cols per wave)
    const unsigned short* abase = apf + (size_t)(nb * 2 + wg) * 7 * 512 + lane * 8;
    const unsigned short* bbase = bp + (size_t)(cb * 6 + wc * 3) * 7 * 512 + lane * 8;

    f32x4 acc[3];
#pragma unroll
    for (int ct = 0; ct < 3; ++ct) acc[ct] = (f32x4){0.f, 0.f, 0.f, 0.f};

#pragma unroll
    for (int kk = 0; kk < 7; ++kk) {
        s16x8 a = *reinterpret_cast<const s16x8*>(abase + kk * 512);
#pragma unroll
        for (int ct = 0; ct < 3; ++ct) {
            s16x8 bfr = *reinterpret_cast<const s16x8*>(bbase + (ct * 7 + kk) * 512);
            acc[ct] = __builtin_amdgcn_mfma_f32_16x16x32_bf16(a, bfr, acc[ct], 0, 0, 0);
        }
    }

    // w16 fragments for the 2 vertex groups (independent of acc; issue early)
    h16x8 wf[2];
#pragma unroll
    for (int g = 0; g < 2; ++g)
        wf[g] = *reinterpret_cast<const h16x8*>(
            &w16[(size_t)(cb * 32 + g * 16 + m) * 32 + q * 8]);

    __syncthreads();          // svt/ssc/strans ready
#pragma unroll
    for (int ct = 0; ct < 3; ++ct) {
        int col_loc = (wc * 3 + ct) * 16 + m;
        int v_loc = col_loc / 3;
        int c = col_loc - 3 * v_loc;
        float vtc = svt[col_loc];
#pragma unroll
        for (int r = 0; r < 4; ++r) {
            int n_loc = wg * 16 + q * 4 + r;
            sm[n_loc][v_loc][c] = (_Float16)(acc[ct][r] + ssc[n_loc] * vtc);
        }
    }

    // ---- stage 2: LBS, wave w owns n-rows [w*8, w*8+8) x all 32 verts
    __syncthreads();                          // sm complete

    const _Float16* anb = an16 + (size_t)(nb * 32 + w * 8) * 512 + m * 32 + q * 8;
    _Float16* vbase = vb + (size_t)(nb * 32 + w * 8) * 3 * VP2 + (size_t)q * VP2
                      + (size_t)cb * 32;
#pragma unroll
    for (int half = 0; half < 2; ++half) {
        h16x8 bf8[4];
#pragma unroll
        for (int i = 0; i < 4; ++i)
            bf8[i] = *reinterpret_cast<const h16x8*>(anb + (size_t)(half * 4 + i) * 512);
#pragma unroll
        for (int i = 0; i < 4; ++i) {
            int nl = w * 8 + half * 4 + i;
            f32x4 at[2];
#pragma unroll
            for (int g = 0; g < 2; ++g) {
                f32x4 z = (f32x4){0.f, 0.f, 0.f, 0.f};
                at[g] = __builtin_amdgcn_mfma_f32_16x16x32_f16(bf8[i], wf[g], z, 0, 0, 0);
            }
            if (q < 3) {
                float tr = strans[nl * 3 + q];
#pragma unroll
                for (int g = 0; g < 2; ++g) {
                    int vl = g * 16 + m;
                    h16x4 p = *reinterpret_cast<const h16x4*>(&sm[nl][vl][0]);
                    float r = at[g][0] * (float)p[0] + at[g][1] * (float)p[1]
                            + at[g][2] * (float)p[2] + at[g][3] + tr;
                    vbase[(size_t)(half * 4 + i) * 3 * VP2 + vl] = (_Float16)r;
                }
            }
        }
    }
}

// ---------------------------------------------------------------------------
// k_regm v6: grid (96 nc-tiles x 9 v-splits) = 864 blocks (~13.5 waves/CU).
// Each wave: 6 K-steps; rb in A-fragment layout (contiguous 1KB wave-loads).
// LDS combine across 4 waves, atomicAdd partials.
__global__ __launch_bounds__(256) void k_regm(const _Float16* __restrict__ rb,
                                              const _Float16* __restrict__ vb,
                                              float* __restrict__ out) {
    int tid = threadIdx.x;
    int lane = tid & 63, w = tid >> 6;
    int m = lane & 15, q = lane >> 4;
    int nct = blockIdx.x;                    // 0..95
    int split = blockIdx.y;                  // 0..8

    const _Float16* brow = vb + (size_t)(nct * 16 + m) * VP2 + q * 8;
    const _Float16* abase = rb + (size_t)(q * 16 + m) * 8;
    int slot = split * 4 + w;                // 0..35
    int vstart = slot * 192;                 // 6 steps of 32 per wave
    int stepBase = slot * 6;

    f32x4 acc[6];
#pragma unroll
    for (int kt = 0; kt < 6; ++kt) acc[kt] = (f32x4){0.f, 0.f, 0.f, 0.f};

#pragma unroll
    for (int s = 0; s < 6; ++s) {
        int off = vstart + s * 32;
        h16x8 b = *reinterpret_cast<const h16x8*>(brow + off);
#pragma unroll
        for (int kt = 0; kt < 6; ++kt) {
            h16x8 a = *reinterpret_cast<const h16x8*>(
                abase + ((size_t)(kt * 216 + stepBase + s) << 9));
            acc[kt] = __builtin_amdgcn_mfma_f32_16x16x32_f16(a, b, acc[kt], 0, 0, 0);
        }
    }
    __shared__ float sm[4][6][256];          // 24 KB
#pragma unroll
    for (int kt = 0; kt < 6; ++kt)
#pragma unroll
        for (int r = 0; r < 4; ++r)
            sm[w][kt][(q * 4 + r) * 16 + m] = acc[kt][r];
    __syncthreads();
    for (int e = tid; e < 6 * 256; e += 256) {
        int kt = e >> 8, i = e & 255;
        float s = sm[0][kt][i] + sm[1][kt][i] + sm[2][kt][i] + sm[3][kt][i];
        int k = kt * 16 + (i >> 4);
        int nc = nct * 16 + (i & 15);
        if (k < NK) {
            int n = nc / 3, c = nc - n * 3;
            atomicAdd(&out[(size_t)n * (NK * 3) + k * 3 + c], s);
        }
    }
}

// ---------------------------------------------------------------------------
extern "C" void kernel_launch(void* const* d_in, const int* in_sizes, int n_in,
                              void* d_out, int out_size, void* d_ws, size_t ws_size,
                              hipStream_t stream) {
    const float* pose  = (const float*)d_in[0];
    const float* betas = (const float*)d_in[1];
    const float* trans = (const float*)d_in[2];
    const float* vt    = (const float*)d_in[3];
    const float* sd    = (const float*)d_in[4];
    const float* jreg  = (const float*)d_in[5];
    const float* pdirs = (const float*)d_in[6];
    const float* lbsw  = (const float*)d_in[7];
    const float* b25   = (const float*)d_in[8];
    const float* face  = (const float*)d_in[9];
    float* ws  = (float*)d_ws;
    float* out = (float*)d_out;
    unsigned short* bf  = (unsigned short*)(ws + BF_OFF);
    unsigned short* apf = bf + APF_U;
    unsigned short* bp  = bf + BP_U;
    _Float16* rb  = (_Float16*)(bf + RB_U);
    _Float16* vb  = (_Float16*)(bf + VB_U);
    _Float16* w16 = (_Float16*)(ws + WT_OFF);
    _Float16* an16 = (_Float16*)(ws + AN_OFF);

    hipMemsetAsync(d_out, 0, (size_t)out_size * sizeof(float), stream);

    k_pre <<<72, 256, 0, stream>>>(jreg, sd, vt, ws);
    k_prep<<<NB_PREP, 256, 0, stream>>>(pdirs, sd, vt, lbsw, b25, face, pose, betas,
                                        bp, rb, w16, apf, an16, ws);
    k_gl  <<<dim3(216, 16), 256, 0, stream>>>(apf, bp, vt, ws, w16, an16, trans, vb);
    k_regm<<<dim3(96, 9), 256, 0, stream>>>(rb, vb, out);
}

// Round 6
// 161.210 us; speedup vs baseline: 1.0597x; 1.0597x over previous
//
#include <hip/hip_runtime.h>

// SMPL body model forward.
// R19: recover R17 (163.9us, best) + two clean deltas. R18's regression
// attributed to: standalone k_pre (0.28 blocks/CU, latency fully exposed)
// and regbf compaction removing the occupancy filler that hid the
// LDS-limited bt section. Reverted both.
//  (1) k_static section order now pre|bt|wt|regbf: the latency-bound pre
//      section (72 blocks, serial column sweeps) dispatches FIRST and hides
//      under bt/regbf bandwidth work instead of running as the kernel tail.
//  (2) k_head FK is level-parallel: joint IDs are level-ordered, tree depth
//      9, <=5 joints x 12 lanes = 60 lanes/level -> 8 parallel steps + 8
//      barriers instead of 23 serial steps + 23 barriers.
// Fixed overhead in timed region: 2x ~43us harness ws-poison fills.

constexpr int N   = 512;
constexpr int V   = 6890;
constexpr int V3  = V * 3;        // 20670
constexpr int NJ  = 24;
constexpr int NB  = 10;
constexpr int NP  = 207;
constexpr int NK  = 95;
constexpr int KP  = 224;          // padded K for pose GEMM
constexpr int VP2 = 6912;         // V padded (108*64)

// workspace layout (float offsets)
constexpr size_t SCALE_OFF = (size_t)N * V3;                  // N
constexpr size_t SJ_OFF    = SCALE_OFF + N;                   // NB*72
constexpr size_t JT_OFF    = SJ_OFF + (size_t)NB * 72;        // 72
constexpr size_t J_OFF     = JT_OFF + 72;
constexpr size_t A_OFF     = J_OFF + (size_t)N * 72;
constexpr size_t BF_OFF    = A_OFF + (size_t)N * 288;         // bf16/fp16 region
// region (ushort offsets)
constexpr size_t APF_U     = 0;                               // apf_sw [N/16][7][64][8] bf16
constexpr int    BP_COLS   = 20736;                           // 108*192 col pad
constexpr size_t BP_U      = (size_t)N * KP;                  // bp_sw [1296][7][64][8] bf16
constexpr size_t RB_U      = BP_U + (size_t)BP_COLS * KP;     // reg fp16 frag [6][216][64][8]
constexpr size_t VB_U      = RB_U + (size_t)96 * VP2;         // verts fp16 [N][3][VP2]
constexpr size_t BF_END_U  = VB_U + (size_t)N * 3 * VP2;
constexpr size_t WT_OFF    = BF_OFF + (BF_END_U + 1) / 2;     // w16 fp16 [VP2][32]
constexpr size_t AN_OFF    = WT_OFF + (size_t)VP2 * 32 / 2;   // an16 fp16 [N][16][32]

// k_static section block counts (pre | bt | wt | regbf)
constexpr int NB_PRE   = 72;
constexpr int NB_BT    = BP_COLS / 64;       // 324
constexpr int NB_WT    = VP2 / 256;          // 27
constexpr int NB_REGBF = (96 * VP2) / 256;   // 2592
constexpr int NB_STATIC = NB_PRE + NB_BT + NB_WT + NB_REGBF;

typedef short s16x8 __attribute__((ext_vector_type(8)));
typedef _Float16 h16x8 __attribute__((ext_vector_type(8)));
typedef _Float16 h16x4 __attribute__((ext_vector_type(4)));
typedef float f32x4 __attribute__((ext_vector_type(4)));

__device__ inline unsigned short f2bf(float f) {
    unsigned u = __float_as_uint(f);
    u += 0x7fffu + ((u >> 16) & 1u);   // round-to-nearest-even
    return (unsigned short)(u >> 16);
}

// ---------------------------------------------------------------------------
// k_static: sectioned batch-independent prep (pre | bt | wt | regbf).
__global__ __launch_bounds__(256) void k_static(const float* __restrict__ pdirs,
                                                const float* __restrict__ sd,
                                                const float* __restrict__ jreg,
                                                const float* __restrict__ vt,
                                                const float* __restrict__ lbsw,
                                                const float* __restrict__ b25,
                                                const float* __restrict__ face,
                                                unsigned short* __restrict__ bp,
                                                _Float16* __restrict__ rb,
                                                _Float16* __restrict__ w16,
                                                float* __restrict__ ws) {
    __shared__ unsigned short smem[KP * 66];     // 29.6 KB, reused per section
    int b = blockIdx.x;
    int tid = threadIdx.x;

    if (b < NB_PRE) {
        // pre: SJ / Jt, block per jc, shuffle reduce. FIRST so its latency
        // overlaps the bandwidth sections instead of forming the tail.
        int jc = b;
        int j = jc / 3, c = jc % 3;
        float acc[NB + 1];
#pragma unroll
        for (int t = 0; t <= NB; ++t) acc[t] = 0.f;
        for (int v = tid; v < V; v += 256) {
            float w = jreg[(size_t)j * V + v];
            int col = v * 3 + c;
#pragma unroll
            for (int k = 0; k < NB; ++k) acc[k] += w * sd[(size_t)k * V3 + col];
            acc[NB] += w * vt[col];
        }
        float* red = reinterpret_cast<float*>(smem);
        int lane = tid & 63, w64 = tid >> 6;
#pragma unroll
        for (int t = 0; t <= NB; ++t) {
            float a = acc[t];
#pragma unroll
            for (int s = 1; s < 64; s <<= 1) a += __shfl_xor(a, s, 64);
            if (lane == 0) red[w64 * 16 + t] = a;
        }
        __syncthreads();
        if (tid <= NB) {
            float s = red[tid] + red[16 + tid] + red[32 + tid] + red[48 + tid];
            if (tid < NB) ws[SJ_OFF + (size_t)tid * 72 + jc] = s;
            else          ws[JT_OFF + jc] = s;
        }
        return;
    }
    b -= NB_PRE;
    if (b < NB_BT) {
        // stage [k][cl] (stride 66: conflict-free gather) then emit FRAGMENT
        // layout bp[(ctg*7+kk)*64+lane][8]
        int c0 = b * 64;
#pragma unroll 4
        for (int i = 0; i < 56; ++i) {
            int e = tid + 256 * i;
            int k = e >> 6, cl = e & 63;
            int col = c0 + cl;
            float v = 0.f;
            if (col < V3) {
                if (k < NP) v = pdirs[(size_t)k * V3 + col];
                else if (k < NP + NB) v = sd[(size_t)(k - NP) * V3 + col];
            }
            smem[k * 66 + cl] = f2bf(v);
        }
        __syncthreads();
        for (int i = 0; i < 7; ++i) {
            int u = tid + 256 * i;                // 0..1791
            int ct_loc = u / 448;
            int rem = u - ct_loc * 448;
            int kk = rem >> 6, lane = rem & 63;
            int m = lane & 15, q = lane >> 4;
            s16x8 r;
#pragma unroll
            for (int j = 0; j < 8; ++j)
                r[j] = (short)smem[(kk * 32 + q * 8 + j) * 66 + ct_loc * 16 + m];
            size_t ctg = (size_t)(c0 >> 4) + ct_loc;
            *reinterpret_cast<s16x8*>(&bp[((ctg * 7 + kk) * 64 + lane) * 8]) = r;
        }
        return;
    }
    b -= NB_BT;
    if (b < NB_WT) {
        // w16[v][k=j] fp16, A-operand layout for the T-MFMA
        float* t = reinterpret_cast<float*>(smem);
        int v0 = b * 256;
        for (int e = tid; e < 256 * 24; e += 256) {
            int g = v0 * 24 + e;
            float val = (g < V * NJ) ? lbsw[g] : 0.f;
            int vv = e / 24, j = e - vv * 24;
            t[vv * 25 + j] = val;
        }
        __syncthreads();
        _Float16* dst = w16 + (size_t)(v0 + tid) * 32;
#pragma unroll
        for (int j = 0; j < 32; ++j)
            dst[j] = (j < NJ) ? (_Float16)t[tid * 25 + j] : (_Float16)0.f;
        return;
    }
    b -= NB_WT;
    {
        // regbf: rb in MFMA A-fragment layout for k_regm (1 elem/thread;
        // the many trivial blocks double as occupancy filler for bt).
        int t = b * 256 + tid;
        int k = t / VP2, v = t - k * VP2;
        float val = 0.f;
        if (v < V && k < NK)
            val = (k < 25) ? b25[(size_t)k * V + v] : face[(size_t)(k - 25) * V + v];
        int kt = k >> 4, m16 = k & 15;
        int step = v >> 5, q8 = (v >> 3) & 3, j = v & 7;
        rb[((size_t)(kt * 216 + step) * 64 + q8 * 16 + m16) * 8 + j] = (_Float16)val;
    }
}

// ---------------------------------------------------------------------------
// k_head: scale + J + apf(fragment layout) + level-parallel FK + an16.
// One wave per n. Joint IDs are level-ordered; tree depth 9, <=5 joints
// (60 lanes) per level.
__global__ __launch_bounds__(64) void k_head(const float* __restrict__ pose,
                                             const float* __restrict__ betas,
                                             const float* __restrict__ vt,
                                             const float* __restrict__ sd,
                                             float* __restrict__ ws,
                                             unsigned short* __restrict__ apf,
                                             _Float16* __restrict__ an16) {
    int n = blockIdx.x;
    int tid = threadIdx.x;
    __shared__ float sval[4];
    __shared__ float Jl[NJ * 3];
    __shared__ float G[NJ * 12];
    __shared__ unsigned short pfsh[KP];

    const int idx4[4] = {2802 * 3 + 1, 6262 * 3 + 1, 2237 * 3 + 1, 6728 * 3 + 1};
    if (tid < 4) {
        float a = vt[idx4[tid]];
#pragma unroll
        for (int k = 0; k < NB; ++k)
            a += betas[n * NB + k] * sd[(size_t)k * V3 + idx4[tid]];
        sval[tid] = a;
    }
    __syncthreads();
    float scale = 1.66f / (sval[0] + sval[1] - sval[2] - sval[3]);
    if (tid == 0) ws[SCALE_OFF + n] = scale;

    for (int k = tid; k < KP; k += 64) {
        float v = 0.f;
        if (k < NP) {
            v = pose[(size_t)n * 216 + 9 + k];
            int km = k % 9;
            if (km == 0 || km == 4 || km == 8) v -= 1.f;
        } else if (k < NP + NB) {
            v = scale * betas[n * NB + (k - NP)];
        }
        pfsh[k] = f2bf(v);
    }
    for (int e = tid; e < 72; e += 64) {
        float a = ws[JT_OFF + e];
#pragma unroll
        for (int k = 0; k < NB; ++k)
            a += betas[n * NB + k] * ws[SJ_OFF + (size_t)k * 72 + e];
        Jl[e] = scale * a;
    }
    __syncthreads();
    // apf fragment layout: [(n/16)*7+kk][lane=q*16+(n&15)][8]
    if (tid < 28) {
        int kk = tid >> 2, q = tid & 3;
        s16x8 r;
#pragma unroll
        for (int j = 0; j < 8; ++j) r[j] = (short)pfsh[kk * 32 + q * 8 + j];
        size_t off = ((size_t)(n >> 4) * 7 + kk) * 64 + q * 16 + (n & 15);
        *reinterpret_cast<s16x8*>(&apf[off * 8]) = r;
    }

    const int par[NJ] = {0,0,0,0,1,2,3,4,5,6,7,8,9,9,9,12,13,14,16,17,18,19,20,21};
    const int LV_OFF[10] = {0, 1, 4, 7, 10, 15, 18, 20, 22, 24};
    if (tid < 12) {
        int r = tid >> 2, c = tid & 3;
        G[tid] = (c < 3) ? pose[(size_t)n * 216 + r * 3 + c] : Jl[r];
    }
    __syncthreads();
#pragma unroll
    for (int l = 1; l <= 8; ++l) {
        int base = LV_OFF[l], cnt = LV_OFF[l + 1] - base;
        int jj = tid / 12, rc = tid - jj * 12;
        if (jj < cnt) {
            int i = base + jj;
            int p = par[i];
            int r = rc >> 2, c = rc & 3;
            const float* gp = &G[p * 12 + r * 4];
            float v;
            if (c < 3) {
                const float* Ri = pose + (size_t)n * 216 + i * 9;
                v = gp[0] * Ri[0 * 3 + c] + gp[1] * Ri[1 * 3 + c] + gp[2] * Ri[2 * 3 + c];
            } else {
                float t0 = Jl[i * 3 + 0] - Jl[p * 3 + 0];
                float t1 = Jl[i * 3 + 1] - Jl[p * 3 + 1];
                float t2 = Jl[i * 3 + 2] - Jl[p * 3 + 2];
                v = gp[0] * t0 + gp[1] * t1 + gp[2] * t2 + gp[3];
            }
            G[i * 12 + rc] = v;
        }
        __syncthreads();
    }
    // an16[n][col(16)][k=j(32)]
    for (int e = tid; e < 512; e += 64) {
        int col = e >> 5, j = e & 31;
        float v = 0.f;
        if (col < 12 && j < NJ) {
            int r = col >> 2, c = col & 3;
            if (c < 3) v = G[j * 12 + r * 4 + c];
            else {
                const float* g = &G[j * 12 + r * 4];
                v = g[3] - (g[0] * Jl[j * 3 + 0] + g[1] * Jl[j * 3 + 1] + g[2] * Jl[j * 3 + 2]);
            }
        }
        an16[(size_t)n * 512 + e] = (_Float16)v;
    }
}

// ---------------------------------------------------------------------------
// k_gl: fused pose-GEMM + LBS, 32v x 32n tiles, grid (216,16). Wave w:
// wg=w&1 picks 16-n group, wc=w>>1 picks 48-col half (3 ct x 7 kk MFMAs).
// Stage 2: wave w owns 8 n-rows x 32 verts via 2 register w16 frags
// (operand-swapped T-MFMA: lane (m,q) gets T[q][0..3] of vertex g*16+m).
// 2 barriers total.
__global__ __launch_bounds__(256) void k_gl(const unsigned short* __restrict__ apf,
                                            const unsigned short* __restrict__ bp,
                                            const float* __restrict__ vt,
                                            const float* __restrict__ ws,
                                            const _Float16* __restrict__ w16,
                                            const _Float16* __restrict__ an16,
                                            const float* __restrict__ trans,
                                            _Float16* __restrict__ vb) {
    int tid = threadIdx.x;
    int lane = tid & 63, w = tid >> 6;
    int m = lane & 15, q = lane >> 4;
    int cb = blockIdx.x;                 // 0..215  (32-v tile)
    int nb = blockIdx.y;                 // 0..15   (32-n tile)
    int wg = w & 1;                      // n 16-group within tile
    int wc = w >> 1;                     // col 48-half

    // posed verts [n(32)][v(33 pad)][c(4)] fp16 = 8.25 KB; row stride 264 B.
    __shared__ __align__(16) _Float16 sm[32][33][4];
    __shared__ float svt[96];
    __shared__ float ssc[32];
    __shared__ float strans[96];
    if (tid < 96) {
        int col = cb * 96 + tid;
        svt[tid] = (col < V3) ? vt[col] : 0.f;
        strans[tid] = trans[nb * 96 + tid];
    }
    if (tid < 32) ssc[tid] = ws[SCALE_OFF + nb * 32 + tid];

    // ---- stage 1: pose GEMM (16 n x 48 cols per wave)
    const unsigned short* abase = apf + (size_t)(nb * 2 + wg) * 7 * 512 + lane * 8;
    const unsigned short* bbase = bp + (size_t)(cb * 6 + wc * 3) * 7 * 512 + lane * 8;

    f32x4 acc[3];
#pragma unroll
    for (int ct = 0; ct < 3; ++ct) acc[ct] = (f32x4){0.f, 0.f, 0.f, 0.f};

#pragma unroll
    for (int kk = 0; kk < 7; ++kk) {
        s16x8 a = *reinterpret_cast<const s16x8*>(abase + kk * 512);
#pragma unroll
        for (int ct = 0; ct < 3; ++ct) {
            s16x8 bfr = *reinterpret_cast<const s16x8*>(bbase + (ct * 7 + kk) * 512);
            acc[ct] = __builtin_amdgcn_mfma_f32_16x16x32_bf16(a, bfr, acc[ct], 0, 0, 0);
        }
    }

    // w16 fragments for the 2 vertex groups (independent of acc; issue early)
    h16x8 wf[2];
#pragma unroll
    for (int g = 0; g < 2; ++g)
        wf[g] = *reinterpret_cast<const h16x8*>(
            &w16[(size_t)(cb * 32 + g * 16 + m) * 32 + q * 8]);

    __syncthreads();          // svt/ssc/strans ready
#pragma unroll
    for (int ct = 0; ct < 3; ++ct) {
        int col_loc = (wc * 3 + ct) * 16 + m;
        int v_loc = col_loc / 3;
        int c = col_loc - 3 * v_loc;
        float vtc = svt[col_loc];
#pragma unroll
        for (int r = 0; r < 4; ++r) {
            int n_loc = wg * 16 + q * 4 + r;
            sm[n_loc][v_loc][c] = (_Float16)(acc[ct][r] + ssc[n_loc] * vtc);
        }
    }

    // ---- stage 2: LBS, wave w owns n-rows [w*8, w*8+8) x all 32 verts
    __syncthreads();                          // sm complete

    const _Float16* anb = an16 + (size_t)(nb * 32 + w * 8) * 512 + m * 32 + q * 8;
    _Float16* vbase = vb + (size_t)(nb * 32 + w * 8) * 3 * VP2 + (size_t)q * VP2
                      + (size_t)cb * 32;
#pragma unroll
    for (int half = 0; half < 2; ++half) {
        h16x8 bf8[4];
#pragma unroll
        for (int i = 0; i < 4; ++i)
            bf8[i] = *reinterpret_cast<const h16x8*>(anb + (size_t)(half * 4 + i) * 512);
#pragma unroll
        for (int i = 0; i < 4; ++i) {
            int nl = w * 8 + half * 4 + i;
            f32x4 at[2];
#pragma unroll
            for (int g = 0; g < 2; ++g) {
                f32x4 z = (f32x4){0.f, 0.f, 0.f, 0.f};
                at[g] = __builtin_amdgcn_mfma_f32_16x16x32_f16(bf8[i], wf[g], z, 0, 0, 0);
            }
            if (q < 3) {
                float tr = strans[nl * 3 + q];
#pragma unroll
                for (int g = 0; g < 2; ++g) {
                    int vl = g * 16 + m;
                    h16x4 p = *reinterpret_cast<const h16x4*>(&sm[nl][vl][0]);
                    float r = at[g][0] * (float)p[0] + at[g][1] * (float)p[1]
                            + at[g][2] * (float)p[2] + at[g][3] + tr;
                    vbase[(size_t)(half * 4 + i) * 3 * VP2 + vl] = (_Float16)r;
                }
            }
        }
    }
}

// ---------------------------------------------------------------------------
// k_regm: grid (96 nc-tiles x 6 v-splits) = 576 blocks, 4 waves, 9 K-steps.
// rb in A-fragment layout (contiguous 1KB wave-loads). LDS combine across
// 4 waves, atomicAdd partials.
__global__ __launch_bounds__(256) void k_regm(const _Float16* __restrict__ rb,
                                              const _Float16* __restrict__ vb,
                                              float* __restrict__ out) {
    int tid = threadIdx.x;
    int lane = tid & 63, w = tid >> 6;
    int m = lane & 15, q = lane >> 4;
    int nct = blockIdx.x;                    // 0..95
    int split = blockIdx.y;                  // 0..5

    const _Float16* brow = vb + (size_t)(nct * 16 + m) * VP2 + q * 8;
    const _Float16* abase = rb + (size_t)(q * 16 + m) * 8;
    int vstart = (split * 4 + w) * 288;      // 9 steps of 32 per wave
    int stepBase = (split * 4 + w) * 9;

    f32x4 acc[6];
#pragma unroll
    for (int kt = 0; kt < 6; ++kt) acc[kt] = (f32x4){0.f, 0.f, 0.f, 0.f};

#pragma unroll
    for (int s = 0; s < 9; ++s) {
        int off = vstart + s * 32;
        h16x8 b = *reinterpret_cast<const h16x8*>(brow + off);
#pragma unroll
        for (int kt = 0; kt < 6; ++kt) {
            h16x8 a = *reinterpret_cast<const h16x8*>(
                abase + ((size_t)(kt * 216 + stepBase + s) << 9));
            acc[kt] = __builtin_amdgcn_mfma_f32_16x16x32_f16(a, b, acc[kt], 0, 0, 0);
        }
    }
    __shared__ float sm[4][6][256];          // 24 KB
#pragma unroll
    for (int kt = 0; kt < 6; ++kt)
#pragma unroll
        for (int r = 0; r < 4; ++r)
            sm[w][kt][(q * 4 + r) * 16 + m] = acc[kt][r];
    __syncthreads();
    for (int e = tid; e < 6 * 256; e += 256) {
        int kt = e >> 8, i = e & 255;
        float s = sm[0][kt][i] + sm[1][kt][i] + sm[2][kt][i] + sm[3][kt][i];
        int k = kt * 16 + (i >> 4);
        int nc = nct * 16 + (i & 15);
        if (k < NK) {
            int n = nc / 3, c = nc - n * 3;
            atomicAdd(&out[(size_t)n * (NK * 3) + k * 3 + c], s);
        }
    }
}

// ---------------------------------------------------------------------------
extern "C" void kernel_launch(void* const* d_in, const int* in_sizes, int n_in,
                              void* d_out, int out_size, void* d_ws, size_t ws_size,
                              hipStream_t stream) {
    const float* pose  = (const float*)d_in[0];
    const float* betas = (const float*)d_in[1];
    const float* trans = (const float*)d_in[2];
    const float* vt    = (const float*)d_in[3];
    const float* sd    = (const float*)d_in[4];
    const float* jreg  = (const float*)d_in[5];
    const float* pdirs = (const float*)d_in[6];
    const float* lbsw  = (const float*)d_in[7];
    const float* b25   = (const float*)d_in[8];
    const float* face  = (const float*)d_in[9];
    float* ws  = (float*)d_ws;
    float* out = (float*)d_out;
    unsigned short* bf  = (unsigned short*)(ws + BF_OFF);
    unsigned short* apf = bf + APF_U;
    unsigned short* bp  = bf + BP_U;
    _Float16* rb  = (_Float16*)(bf + RB_U);
    _Float16* vb  = (_Float16*)(bf + VB_U);
    _Float16* w16 = (_Float16*)(ws + WT_OFF);
    _Float16* an16 = (_Float16*)(ws + AN_OFF);

    hipMemsetAsync(d_out, 0, (size_t)out_size * sizeof(float), stream);

    k_static<<<NB_STATIC, 256, 0, stream>>>(pdirs, sd, jreg, vt, lbsw, b25, face,
                                            bp, rb, w16, ws);
    k_head  <<<N, 64, 0, stream>>>(pose, betas, vt, sd, ws, apf, an16);
    k_gl    <<<dim3(216, 16), 256, 0, stream>>>(apf, bp, vt, ws, w16, an16, trans, vb);
    k_regm  <<<dim3(96, 6), 256, 0, stream>>>(rb, vb, out);
}

// Round 7
// 153.265 us; speedup vs baseline: 1.1146x; 1.0518x over previous
//
#include <hip/hip_runtime.h>

// SMPL body model forward.
// R20: two low-risk edits on the R19 structure (161.2us best).
//  (1) d_out zeroing folded into k_static as a 143-block float4 section
//      (drops the hipMemsetAsync launch; stream order still guarantees
//      zeros before k_regm's atomics). ~2-4us launch overhead saved.
//  (2) bt staging loads vectorized float2 (56 -> 28 VMEM iters), two bf16
//      packed per u32 LDS store (4B-aligned; banks (k+cl2)%32 -> 2
//      lanes/bank = free). V3 even -> 8B alignment holds every row.
// Section order stays pre|zero|bt|wt|regbf (pre's latency hides under the
// bandwidth sections; regbf's trivial blocks backfill occupancy).
// Fixed overhead in timed region: 2x ~43us harness ws-poison fills.

constexpr int N   = 512;
constexpr int V   = 6890;
constexpr int V3  = V * 3;        // 20670
constexpr int NJ  = 24;
constexpr int NB  = 10;
constexpr int NP  = 207;
constexpr int NK  = 95;
constexpr int KP  = 224;          // padded K for pose GEMM
constexpr int VP2 = 6912;         // V padded (108*64)

// workspace layout (float offsets)
constexpr size_t SCALE_OFF = (size_t)N * V3;                  // N
constexpr size_t SJ_OFF    = SCALE_OFF + N;                   // NB*72
constexpr size_t JT_OFF    = SJ_OFF + (size_t)NB * 72;        // 72
constexpr size_t J_OFF     = JT_OFF + 72;
constexpr size_t A_OFF     = J_OFF + (size_t)N * 72;
constexpr size_t BF_OFF    = A_OFF + (size_t)N * 288;         // bf16/fp16 region
// region (ushort offsets)
constexpr size_t APF_U     = 0;                               // apf_sw [N/16][7][64][8] bf16
constexpr int    BP_COLS   = 20736;                           // 108*192 col pad
constexpr size_t BP_U      = (size_t)N * KP;                  // bp_sw [1296][7][64][8] bf16
constexpr size_t RB_U      = BP_U + (size_t)BP_COLS * KP;     // reg fp16 frag [6][216][64][8]
constexpr size_t VB_U      = RB_U + (size_t)96 * VP2;         // verts fp16 [N][3][VP2]
constexpr size_t BF_END_U  = VB_U + (size_t)N * 3 * VP2;
constexpr size_t WT_OFF    = BF_OFF + (BF_END_U + 1) / 2;     // w16 fp16 [VP2][32]
constexpr size_t AN_OFF    = WT_OFF + (size_t)VP2 * 32 / 2;   // an16 fp16 [N][16][32]

// k_static section block counts (pre | zero | bt | wt | regbf)
constexpr int OUT_FLOATS = N * NK * 3;       // 145920
constexpr int NB_PRE   = 72;
constexpr int NB_ZERO  = (OUT_FLOATS / 4 + 255) / 256;   // 143
constexpr int NB_BT    = BP_COLS / 64;       // 324
constexpr int NB_WT    = VP2 / 256;          // 27
constexpr int NB_REGBF = (96 * VP2) / 256;   // 2592
constexpr int NB_STATIC = NB_PRE + NB_ZERO + NB_BT + NB_WT + NB_REGBF;

typedef short s16x8 __attribute__((ext_vector_type(8)));
typedef _Float16 h16x8 __attribute__((ext_vector_type(8)));
typedef _Float16 h16x4 __attribute__((ext_vector_type(4)));
typedef float f32x4 __attribute__((ext_vector_type(4)));

__device__ inline unsigned short f2bf(float f) {
    unsigned u = __float_as_uint(f);
    u += 0x7fffu + ((u >> 16) & 1u);   // round-to-nearest-even
    return (unsigned short)(u >> 16);
}

// ---------------------------------------------------------------------------
// k_static: sectioned batch-independent prep (pre | zero | bt | wt | regbf).
__global__ __launch_bounds__(256) void k_static(const float* __restrict__ pdirs,
                                                const float* __restrict__ sd,
                                                const float* __restrict__ jreg,
                                                const float* __restrict__ vt,
                                                const float* __restrict__ lbsw,
                                                const float* __restrict__ b25,
                                                const float* __restrict__ face,
                                                unsigned short* __restrict__ bp,
                                                _Float16* __restrict__ rb,
                                                _Float16* __restrict__ w16,
                                                float* __restrict__ ws,
                                                float* __restrict__ out) {
    __shared__ unsigned short smem[KP * 66];     // 29.6 KB, reused per section
    int b = blockIdx.x;
    int tid = threadIdx.x;

    if (b < NB_PRE) {
        // pre: SJ / Jt, block per jc, shuffle reduce. FIRST so its latency
        // overlaps the bandwidth sections instead of forming the tail.
        int jc = b;
        int j = jc / 3, c = jc % 3;
        float acc[NB + 1];
#pragma unroll
        for (int t = 0; t <= NB; ++t) acc[t] = 0.f;
        for (int v = tid; v < V; v += 256) {
            float w = jreg[(size_t)j * V + v];
            int col = v * 3 + c;
#pragma unroll
            for (int k = 0; k < NB; ++k) acc[k] += w * sd[(size_t)k * V3 + col];
            acc[NB] += w * vt[col];
        }
        float* red = reinterpret_cast<float*>(smem);
        int lane = tid & 63, w64 = tid >> 6;
#pragma unroll
        for (int t = 0; t <= NB; ++t) {
            float a = acc[t];
#pragma unroll
            for (int s = 1; s < 64; s <<= 1) a += __shfl_xor(a, s, 64);
            if (lane == 0) red[w64 * 16 + t] = a;
        }
        __syncthreads();
        if (tid <= NB) {
            float s = red[tid] + red[16 + tid] + red[32 + tid] + red[48 + tid];
            if (tid < NB) ws[SJ_OFF + (size_t)tid * 72 + jc] = s;
            else          ws[JT_OFF + jc] = s;
        }
        return;
    }
    b -= NB_PRE;
    if (b < NB_ZERO) {
        // zero d_out (replaces hipMemsetAsync; k_static precedes k_regm in
        // stream order, so atomics land on zeros).
        int t4 = b * 256 + tid;
        if (t4 < OUT_FLOATS / 4)
            *reinterpret_cast<f32x4*>(&out[(size_t)t4 * 4]) =
                (f32x4){0.f, 0.f, 0.f, 0.f};
        return;
    }
    b -= NB_ZERO;
    if (b < NB_BT) {
        // stage [k][cl] (stride 66: conflict-free gather) then emit FRAGMENT
        // layout bp[(ctg*7+kk)*64+lane][8]. float2 loads: 28 iters, 2 bf16
        // packed per u32 LDS store.
        int c0 = b * 64;
#pragma unroll 4
        for (int i = 0; i < 28; ++i) {
            int e2 = tid + 256 * i;              // 0..7167
            int k = e2 >> 5, cl2 = e2 & 31;      // row, float2-within-row
            int col = c0 + cl2 * 2;
            float x = 0.f, y = 0.f;
            if (col < V3) {
                if (k < NP) {
                    const float2 p = *reinterpret_cast<const float2*>(
                        &pdirs[(size_t)k * V3 + col]);
                    x = p.x; y = p.y;
                } else if (k < NP + NB) {
                    const float2 p = *reinterpret_cast<const float2*>(
                        &sd[(size_t)(k - NP) * V3 + col]);
                    x = p.x; y = p.y;
                }
            }
            unsigned pk = (unsigned)f2bf(x) | ((unsigned)f2bf(y) << 16);
            *reinterpret_cast<unsigned*>(&smem[k * 66 + cl2 * 2]) = pk;
        }
        __syncthreads();
        for (int i = 0; i < 7; ++i) {
            int u = tid + 256 * i;                // 0..1791
            int ct_loc = u / 448;
            int rem = u - ct_loc * 448;
            int kk = rem >> 6, lane = rem & 63;
            int m = lane & 15, q = lane >> 4;
            s16x8 r;
#pragma unroll
            for (int j = 0; j < 8; ++j)
                r[j] = (short)smem[(kk * 32 + q * 8 + j) * 66 + ct_loc * 16 + m];
            size_t ctg = (size_t)(c0 >> 4) + ct_loc;
            *reinterpret_cast<s16x8*>(&bp[((ctg * 7 + kk) * 64 + lane) * 8]) = r;
        }
        return;
    }
    b -= NB_BT;
    if (b < NB_WT) {
        // w16[v][k=j] fp16, A-operand layout for the T-MFMA
        float* t = reinterpret_cast<float*>(smem);
        int v0 = b * 256;
        for (int e = tid; e < 256 * 24; e += 256) {
            int g = v0 * 24 + e;
            float val = (g < V * NJ) ? lbsw[g] : 0.f;
            int vv = e / 24, j = e - vv * 24;
            t[vv * 25 + j] = val;
        }
        __syncthreads();
        _Float16* dst = w16 + (size_t)(v0 + tid) * 32;
#pragma unroll
        for (int j = 0; j < 32; ++j)
            dst[j] = (j < NJ) ? (_Float16)t[tid * 25 + j] : (_Float16)0.f;
        return;
    }
    b -= NB_WT;
    {
        // regbf: rb in MFMA A-fragment layout for k_regm (1 elem/thread;
        // the many trivial blocks double as occupancy filler for bt).
        int t = b * 256 + tid;
        int k = t / VP2, v = t - k * VP2;
        float val = 0.f;
        if (v < V && k < NK)
            val = (k < 25) ? b25[(size_t)k * V + v] : face[(size_t)(k - 25) * V + v];
        int kt = k >> 4, m16 = k & 15;
        int step = v >> 5, q8 = (v >> 3) & 3, j = v & 7;
        rb[((size_t)(kt * 216 + step) * 64 + q8 * 16 + m16) * 8 + j] = (_Float16)val;
    }
}

// ---------------------------------------------------------------------------
// k_head: scale + J + apf(fragment layout) + level-parallel FK + an16.
// One wave per n. Joint IDs are level-ordered; tree depth 9, <=5 joints
// (60 lanes) per level.
__global__ __launch_bounds__(64) void k_head(const float* __restrict__ pose,
                                             const float* __restrict__ betas,
                                             const float* __restrict__ vt,
                                             const float* __restrict__ sd,
                                             float* __restrict__ ws,
                                             unsigned short* __restrict__ apf,
                                             _Float16* __restrict__ an16) {
    int n = blockIdx.x;
    int tid = threadIdx.x;
    __shared__ float sval[4];
    __shared__ float Jl[NJ * 3];
    __shared__ float G[NJ * 12];
    __shared__ unsigned short pfsh[KP];

    const int idx4[4] = {2802 * 3 + 1, 6262 * 3 + 1, 2237 * 3 + 1, 6728 * 3 + 1};
    if (tid < 4) {
        float a = vt[idx4[tid]];
#pragma unroll
        for (int k = 0; k < NB; ++k)
            a += betas[n * NB + k] * sd[(size_t)k * V3 + idx4[tid]];
        sval[tid] = a;
    }
    __syncthreads();
    float scale = 1.66f / (sval[0] + sval[1] - sval[2] - sval[3]);
    if (tid == 0) ws[SCALE_OFF + n] = scale;

    for (int k = tid; k < KP; k += 64) {
        float v = 0.f;
        if (k < NP) {
            v = pose[(size_t)n * 216 + 9 + k];
            int km = k % 9;
            if (km == 0 || km == 4 || km == 8) v -= 1.f;
        } else if (k < NP + NB) {
            v = scale * betas[n * NB + (k - NP)];
        }
        pfsh[k] = f2bf(v);
    }
    for (int e = tid; e < 72; e += 64) {
        float a = ws[JT_OFF + e];
#pragma unroll
        for (int k = 0; k < NB; ++k)
            a += betas[n * NB + k] * ws[SJ_OFF + (size_t)k * 72 + e];
        Jl[e] = scale * a;
    }
    __syncthreads();
    // apf fragment layout: [(n/16)*7+kk][lane=q*16+(n&15)][8]
    if (tid < 28) {
        int kk = tid >> 2, q = tid & 3;
        s16x8 r;
#pragma unroll
        for (int j = 0; j < 8; ++j) r[j] = (short)pfsh[kk * 32 + q * 8 + j];
        size_t off = ((size_t)(n >> 4) * 7 + kk) * 64 + q * 16 + (n & 15);
        *reinterpret_cast<s16x8*>(&apf[off * 8]) = r;
    }

    const int par[NJ] = {0,0,0,0,1,2,3,4,5,6,7,8,9,9,9,12,13,14,16,17,18,19,20,21};
    const int LV_OFF[10] = {0, 1, 4, 7, 10, 15, 18, 20, 22, 24};
    if (tid < 12) {
        int r = tid >> 2, c = tid & 3;
        G[tid] = (c < 3) ? pose[(size_t)n * 216 + r * 3 + c] : Jl[r];
    }
    __syncthreads();
#pragma unroll
    for (int l = 1; l <= 8; ++l) {
        int base = LV_OFF[l], cnt = LV_OFF[l + 1] - base;
        int jj = tid / 12, rc = tid - jj * 12;
        if (jj < cnt) {
            int i = base + jj;
            int p = par[i];
            int r = rc >> 2, c = rc & 3;
            const float* gp = &G[p * 12 + r * 4];
            float v;
            if (c < 3) {
                const float* Ri = pose + (size_t)n * 216 + i * 9;
                v = gp[0] * Ri[0 * 3 + c] + gp[1] * Ri[1 * 3 + c] + gp[2] * Ri[2 * 3 + c];
            } else {
                float t0 = Jl[i * 3 + 0] - Jl[p * 3 + 0];
                float t1 = Jl[i * 3 + 1] - Jl[p * 3 + 1];
                float t2 = Jl[i * 3 + 2] - Jl[p * 3 + 2];
                v = gp[0] * t0 + gp[1] * t1 + gp[2] * t2 + gp[3];
            }
            G[i * 12 + rc] = v;
        }
        __syncthreads();
    }
    // an16[n][col(16)][k=j(32)]
    for (int e = tid; e < 512; e += 64) {
        int col = e >> 5, j = e & 31;
        float v = 0.f;
        if (col < 12 && j < NJ) {
            int r = col >> 2, c = col & 3;
            if (c < 3) v = G[j * 12 + r * 4 + c];
            else {
                const float* g = &G[j * 12 + r * 4];
                v = g[3] - (g[0] * Jl[j * 3 + 0] + g[1] * Jl[j * 3 + 1] + g[2] * Jl[j * 3 + 2]);
            }
        }
        an16[(size_t)n * 512 + e] = (_Float16)v;
    }
}

// ---------------------------------------------------------------------------
// k_gl: fused pose-GEMM + LBS, 32v x 32n tiles, grid (216,16). Wave w:
// wg=w&1 picks 16-n group, wc=w>>1 picks 48-col half (3 ct x 7 kk MFMAs).
// Stage 2: wave w owns 8 n-rows x 32 verts via 2 register w16 frags
// (operand-swapped T-MFMA: lane (m,q) gets T[q][0..3] of vertex g*16+m).
// 2 barriers total.
__global__ __launch_bounds__(256) void k_gl(const unsigned short* __restrict__ apf,
                                            const unsigned short* __restrict__ bp,
                                            const float* __restrict__ vt,
                                            const float* __restrict__ ws,
                                            const _Float16* __restrict__ w16,
                                            const _Float16* __restrict__ an16,
                                            const float* __restrict__ trans,
                                            _Float16* __restrict__ vb) {
    int tid = threadIdx.x;
    int lane = tid & 63, w = tid >> 6;
    int m = lane & 15, q = lane >> 4;
    int cb = blockIdx.x;                 // 0..215  (32-v tile)
    int nb = blockIdx.y;                 // 0..15   (32-n tile)
    int wg = w & 1;                      // n 16-group within tile
    int wc = w >> 1;                     // col 48-half

    // posed verts [n(32)][v(33 pad)][c(4)] fp16 = 8.25 KB; row stride 264 B.
    __shared__ __align__(16) _Float16 sm[32][33][4];
    __shared__ float svt[96];
    __shared__ float ssc[32];
    __shared__ float strans[96];
    if (tid < 96) {
        int col = cb * 96 + tid;
        svt[tid] = (col < V3) ? vt[col] : 0.f;
        strans[tid] = trans[nb * 96 + tid];
    }
    if (tid < 32) ssc[tid] = ws[SCALE_OFF + nb * 32 + tid];

    // ---- stage 1: pose GEMM (16 n x 48 cols per wave)
    const unsigned short* abase = apf + (size_t)(nb * 2 + wg) * 7 * 512 + lane * 8;
    const unsigned short* bbase = bp + (size_t)(cb * 6 + wc * 3) * 7 * 512 + lane * 8;

    f32x4 acc[3];
#pragma unroll
    for (int ct = 0; ct < 3; ++ct) acc[ct] = (f32x4){0.f, 0.f, 0.f, 0.f};

#pragma unroll
    for (int kk = 0; kk < 7; ++kk) {
        s16x8 a = *reinterpret_cast<const s16x8*>(abase + kk * 512);
#pragma unroll
        for (int ct = 0; ct < 3; ++ct) {
            s16x8 bfr = *reinterpret_cast<const s16x8*>(bbase + (ct * 7 + kk) * 512);
            acc[ct] = __builtin_amdgcn_mfma_f32_16x16x32_bf16(a, bfr, acc[ct], 0, 0, 0);
        }
    }

    // w16 fragments for the 2 vertex groups (independent of acc; issue early)
    h16x8 wf[2];
#pragma unroll
    for (int g = 0; g < 2; ++g)
        wf[g] = *reinterpret_cast<const h16x8*>(
            &w16[(size_t)(cb * 32 + g * 16 + m) * 32 + q * 8]);

    __syncthreads();          // svt/ssc/strans ready
#pragma unroll
    for (int ct = 0; ct < 3; ++ct) {
        int col_loc = (wc * 3 + ct) * 16 + m;
        int v_loc = col_loc / 3;
        int c = col_loc - 3 * v_loc;
        float vtc = svt[col_loc];
#pragma unroll
        for (int r = 0; r < 4; ++r) {
            int n_loc = wg * 16 + q * 4 + r;
            sm[n_loc][v_loc][c] = (_Float16)(acc[ct][r] + ssc[n_loc] * vtc);
        }
    }

    // ---- stage 2: LBS, wave w owns n-rows [w*8, w*8+8) x all 32 verts
    __syncthreads();                          // sm complete

    const _Float16* anb = an16 + (size_t)(nb * 32 + w * 8) * 512 + m * 32 + q * 8;
    _Float16* vbase = vb + (size_t)(nb * 32 + w * 8) * 3 * VP2 + (size_t)q * VP2
                      + (size_t)cb * 32;
#pragma unroll
    for (int half = 0; half < 2; ++half) {
        h16x8 bf8[4];
#pragma unroll
        for (int i = 0; i < 4; ++i)
            bf8[i] = *reinterpret_cast<const h16x8*>(anb + (size_t)(half * 4 + i) * 512);
#pragma unroll
        for (int i = 0; i < 4; ++i) {
            int nl = w * 8 + half * 4 + i;
            f32x4 at[2];
#pragma unroll
            for (int g = 0; g < 2; ++g) {
                f32x4 z = (f32x4){0.f, 0.f, 0.f, 0.f};
                at[g] = __builtin_amdgcn_mfma_f32_16x16x32_f16(bf8[i], wf[g], z, 0, 0, 0);
            }
            if (q < 3) {
                float tr = strans[nl * 3 + q];
#pragma unroll
                for (int g = 0; g < 2; ++g) {
                    int vl = g * 16 + m;
                    h16x4 p = *reinterpret_cast<const h16x4*>(&sm[nl][vl][0]);
                    float r = at[g][0] * (float)p[0] + at[g][1] * (float)p[1]
                            + at[g][2] * (float)p[2] + at[g][3] + tr;
                    vbase[(size_t)(half * 4 + i) * 3 * VP2 + vl] = (_Float16)r;
                }
            }
        }
    }
}

// ---------------------------------------------------------------------------
// k_regm: grid (96 nc-tiles x 6 v-splits) = 576 blocks, 4 waves, 9 K-steps.
// rb in A-fragment layout (contiguous 1KB wave-loads). LDS combine across
// 4 waves, atomicAdd partials.
__global__ __launch_bounds__(256) void k_regm(const _Float16* __restrict__ rb,
                                              const _Float16* __restrict__ vb,
                                              float* __restrict__ out) {
    int tid = threadIdx.x;
    int lane = tid & 63, w = tid >> 6;
    int m = lane & 15, q = lane >> 4;
    int nct = blockIdx.x;                    // 0..95
    int split = blockIdx.y;                  // 0..5

    const _Float16* brow = vb + (size_t)(nct * 16 + m) * VP2 + q * 8;
    const _Float16* abase = rb + (size_t)(q * 16 + m) * 8;
    int vstart = (split * 4 + w) * 288;      // 9 steps of 32 per wave
    int stepBase = (split * 4 + w) * 9;

    f32x4 acc[6];
#pragma unroll
    for (int kt = 0; kt < 6; ++kt) acc[kt] = (f32x4){0.f, 0.f, 0.f, 0.f};

#pragma unroll
    for (int s = 0; s < 9; ++s) {
        int off = vstart + s * 32;
        h16x8 b = *reinterpret_cast<const h16x8*>(brow + off);
#pragma unroll
        for (int kt = 0; kt < 6; ++kt) {
            h16x8 a = *reinterpret_cast<const h16x8*>(
                abase + ((size_t)(kt * 216 + stepBase + s) << 9));
            acc[kt] = __builtin_amdgcn_mfma_f32_16x16x32_f16(a, b, acc[kt], 0, 0, 0);
        }
    }
    __shared__ float sm[4][6][256];          // 24 KB
#pragma unroll
    for (int kt = 0; kt < 6; ++kt)
#pragma unroll
        for (int r = 0; r < 4; ++r)
            sm[w][kt][(q * 4 + r) * 16 + m] = acc[kt][r];
    __syncthreads();
    for (int e = tid; e < 6 * 256; e += 256) {
        int kt = e >> 8, i = e & 255;
        float s = sm[0][kt][i] + sm[1][kt][i] + sm[2][kt][i] + sm[3][kt][i];
        int k = kt * 16 + (i >> 4);
        int nc = nct * 16 + (i & 15);
        if (k < NK) {
            int n = nc / 3, c = nc - n * 3;
            atomicAdd(&out[(size_t)n * (NK * 3) + k * 3 + c], s);
        }
    }
}

// ---------------------------------------------------------------------------
extern "C" void kernel_launch(void* const* d_in, const int* in_sizes, int n_in,
                              void* d_out, int out_size, void* d_ws, size_t ws_size,
                              hipStream_t stream) {
    const float* pose  = (const float*)d_in[0];
    const float* betas = (const float*)d_in[1];
    const float* trans = (const float*)d_in[2];
    const float* vt    = (const float*)d_in[3];
    const float* sd    = (const float*)d_in[4];
    const float* jreg  = (const float*)d_in[5];
    const float* pdirs = (const float*)d_in[6];
    const float* lbsw  = (const float*)d_in[7];
    const float* b25   = (const float*)d_in[8];
    const float* face  = (const float*)d_in[9];
    float* ws  = (float*)d_ws;
    float* out = (float*)d_out;
    unsigned short* bf  = (unsigned short*)(ws + BF_OFF);
    unsigned short* apf = bf + APF_U;
    unsigned short* bp  = bf + BP_U;
    _Float16* rb  = (_Float16*)(bf + RB_U);
    _Float16* vb  = (_Float16*)(bf + VB_U);
    _Float16* w16 = (_Float16*)(ws + WT_OFF);
    _Float16* an16 = (_Float16*)(ws + AN_OFF);

    k_static<<<NB_STATIC, 256, 0, stream>>>(pdirs, sd, jreg, vt, lbsw, b25, face,
                                            bp, rb, w16, ws, out);
    k_head  <<<N, 64, 0, stream>>>(pose, betas, vt, sd, ws, apf, an16);
    k_gl    <<<dim3(216, 16), 256, 0, stream>>>(apf, bp, vt, ws, w16, an16, trans, vb);
    k_regm  <<<dim3(96, 6), 256, 0, stream>>>(rb, vb, out);
}

// Round 8
// 152.839 us; speedup vs baseline: 1.1177x; 1.0028x over previous
//
#include <hip/hip_runtime.h>

// SMPL body model forward.
// R21: vb stored in k_regm's B-fragment layout (written by k_gl).
// Old: vb[n][c][VP2] -- k_regm's B-load gathered 16B/lane from 16 rows at
// 13.8KB stride = 16 cache lines per wave-load on the kernel's dominant
// 21MB stream. New: vb_frag[nct][vstep][lane64][8] with nct=(n*3+c)/16,
// vstep=v/32 (== cb for k_gl's 32-v tiles), lane=((v%32)/8)*16+(nc%16),
// elem=v%8. k_regm B-loads become contiguous 1KB wave-loads (4 lines, 4x
// fewer transactions); k_gl store coalescing ~unchanged (6x16B vs 3x32B
// chunks per store). Buffer size bit-identical. Everything else == R20
// (153.3us best: fills 2x43.5 fixed + ~65us kernels).

constexpr int N   = 512;
constexpr int V   = 6890;
constexpr int V3  = V * 3;        // 20670
constexpr int NJ  = 24;
constexpr int NB  = 10;
constexpr int NP  = 207;
constexpr int NK  = 95;
constexpr int KP  = 224;          // padded K for pose GEMM
constexpr int VP2 = 6912;         // V padded (108*64)

// workspace layout (float offsets)
constexpr size_t SCALE_OFF = (size_t)N * V3;                  // N
constexpr size_t SJ_OFF    = SCALE_OFF + N;                   // NB*72
constexpr size_t JT_OFF    = SJ_OFF + (size_t)NB * 72;        // 72
constexpr size_t J_OFF     = JT_OFF + 72;
constexpr size_t A_OFF     = J_OFF + (size_t)N * 72;
constexpr size_t BF_OFF    = A_OFF + (size_t)N * 288;         // bf16/fp16 region
// region (ushort offsets)
constexpr size_t APF_U     = 0;                               // apf_sw [N/16][7][64][8] bf16
constexpr int    BP_COLS   = 20736;                           // 108*192 col pad
constexpr size_t BP_U      = (size_t)N * KP;                  // bp_sw [1296][7][64][8] bf16
constexpr size_t RB_U      = BP_U + (size_t)BP_COLS * KP;     // reg fp16 frag [6][216][64][8]
constexpr size_t VB_U      = RB_U + (size_t)96 * VP2;         // verts fp16 frag [96][216][64][8]
constexpr size_t BF_END_U  = VB_U + (size_t)N * 3 * VP2;
constexpr size_t WT_OFF    = BF_OFF + (BF_END_U + 1) / 2;     // w16 fp16 [VP2][32]
constexpr size_t AN_OFF    = WT_OFF + (size_t)VP2 * 32 / 2;   // an16 fp16 [N][16][32]

// k_static section block counts (pre | zero | bt | wt | regbf)
constexpr int OUT_FLOATS = N * NK * 3;       // 145920
constexpr int NB_PRE   = 72;
constexpr int NB_ZERO  = (OUT_FLOATS / 4 + 255) / 256;   // 143
constexpr int NB_BT    = BP_COLS / 64;       // 324
constexpr int NB_WT    = VP2 / 256;          // 27
constexpr int NB_REGBF = (96 * VP2) / 256;   // 2592
constexpr int NB_STATIC = NB_PRE + NB_ZERO + NB_BT + NB_WT + NB_REGBF;

typedef short s16x8 __attribute__((ext_vector_type(8)));
typedef _Float16 h16x8 __attribute__((ext_vector_type(8)));
typedef _Float16 h16x4 __attribute__((ext_vector_type(4)));
typedef float f32x4 __attribute__((ext_vector_type(4)));

__device__ inline unsigned short f2bf(float f) {
    unsigned u = __float_as_uint(f);
    u += 0x7fffu + ((u >> 16) & 1u);   // round-to-nearest-even
    return (unsigned short)(u >> 16);
}

// ---------------------------------------------------------------------------
// k_static: sectioned batch-independent prep (pre | zero | bt | wt | regbf).
__global__ __launch_bounds__(256) void k_static(const float* __restrict__ pdirs,
                                                const float* __restrict__ sd,
                                                const float* __restrict__ jreg,
                                                const float* __restrict__ vt,
                                                const float* __restrict__ lbsw,
                                                const float* __restrict__ b25,
                                                const float* __restrict__ face,
                                                unsigned short* __restrict__ bp,
                                                _Float16* __restrict__ rb,
                                                _Float16* __restrict__ w16,
                                                float* __restrict__ ws,
                                                float* __restrict__ out) {
    __shared__ unsigned short smem[KP * 66];     // 29.6 KB, reused per section
    int b = blockIdx.x;
    int tid = threadIdx.x;

    if (b < NB_PRE) {
        // pre: SJ / Jt, block per jc, shuffle reduce. FIRST so its latency
        // overlaps the bandwidth sections instead of forming the tail.
        int jc = b;
        int j = jc / 3, c = jc % 3;
        float acc[NB + 1];
#pragma unroll
        for (int t = 0; t <= NB; ++t) acc[t] = 0.f;
        for (int v = tid; v < V; v += 256) {
            float w = jreg[(size_t)j * V + v];
            int col = v * 3 + c;
#pragma unroll
            for (int k = 0; k < NB; ++k) acc[k] += w * sd[(size_t)k * V3 + col];
            acc[NB] += w * vt[col];
        }
        float* red = reinterpret_cast<float*>(smem);
        int lane = tid & 63, w64 = tid >> 6;
#pragma unroll
        for (int t = 0; t <= NB; ++t) {
            float a = acc[t];
#pragma unroll
            for (int s = 1; s < 64; s <<= 1) a += __shfl_xor(a, s, 64);
            if (lane == 0) red[w64 * 16 + t] = a;
        }
        __syncthreads();
        if (tid <= NB) {
            float s = red[tid] + red[16 + tid] + red[32 + tid] + red[48 + tid];
            if (tid < NB) ws[SJ_OFF + (size_t)tid * 72 + jc] = s;
            else          ws[JT_OFF + jc] = s;
        }
        return;
    }
    b -= NB_PRE;
    if (b < NB_ZERO) {
        // zero d_out (replaces hipMemsetAsync; k_static precedes k_regm in
        // stream order, so atomics land on zeros).
        int t4 = b * 256 + tid;
        if (t4 < OUT_FLOATS / 4)
            *reinterpret_cast<f32x4*>(&out[(size_t)t4 * 4]) =
                (f32x4){0.f, 0.f, 0.f, 0.f};
        return;
    }
    b -= NB_ZERO;
    if (b < NB_BT) {
        // stage [k][cl] (stride 66: conflict-free gather) then emit FRAGMENT
        // layout bp[(ctg*7+kk)*64+lane][8]. float2 loads: 28 iters, 2 bf16
        // packed per u32 LDS store.
        int c0 = b * 64;
#pragma unroll 4
        for (int i = 0; i < 28; ++i) {
            int e2 = tid + 256 * i;              // 0..7167
            int k = e2 >> 5, cl2 = e2 & 31;      // row, float2-within-row
            int col = c0 + cl2 * 2;
            float x = 0.f, y = 0.f;
            if (col < V3) {
                if (k < NP) {
                    const float2 p = *reinterpret_cast<const float2*>(
                        &pdirs[(size_t)k * V3 + col]);
                    x = p.x; y = p.y;
                } else if (k < NP + NB) {
                    const float2 p = *reinterpret_cast<const float2*>(
                        &sd[(size_t)(k - NP) * V3 + col]);
                    x = p.x; y = p.y;
                }
            }
            unsigned pk = (unsigned)f2bf(x) | ((unsigned)f2bf(y) << 16);
            *reinterpret_cast<unsigned*>(&smem[k * 66 + cl2 * 2]) = pk;
        }
        __syncthreads();
        for (int i = 0; i < 7; ++i) {
            int u = tid + 256 * i;                // 0..1791
            int ct_loc = u / 448;
            int rem = u - ct_loc * 448;
            int kk = rem >> 6, lane = rem & 63;
            int m = lane & 15, q = lane >> 4;
            s16x8 r;
#pragma unroll
            for (int j = 0; j < 8; ++j)
                r[j] = (short)smem[(kk * 32 + q * 8 + j) * 66 + ct_loc * 16 + m];
            size_t ctg = (size_t)(c0 >> 4) + ct_loc;
            *reinterpret_cast<s16x8*>(&bp[((ctg * 7 + kk) * 64 + lane) * 8]) = r;
        }
        return;
    }
    b -= NB_BT;
    if (b < NB_WT) {
        // w16[v][k=j] fp16, A-operand layout for the T-MFMA
        float* t = reinterpret_cast<float*>(smem);
        int v0 = b * 256;
        for (int e = tid; e < 256 * 24; e += 256) {
            int g = v0 * 24 + e;
            float val = (g < V * NJ) ? lbsw[g] : 0.f;
            int vv = e / 24, j = e - vv * 24;
            t[vv * 25 + j] = val;
        }
        __syncthreads();
        _Float16* dst = w16 + (size_t)(v0 + tid) * 32;
#pragma unroll
        for (int j = 0; j < 32; ++j)
            dst[j] = (j < NJ) ? (_Float16)t[tid * 25 + j] : (_Float16)0.f;
        return;
    }
    b -= NB_WT;
    {
        // regbf: rb in MFMA A-fragment layout for k_regm (1 elem/thread;
        // the many trivial blocks double as occupancy filler for bt).
        int t = b * 256 + tid;
        int k = t / VP2, v = t - k * VP2;
        float val = 0.f;
        if (v < V && k < NK)
            val = (k < 25) ? b25[(size_t)k * V + v] : face[(size_t)(k - 25) * V + v];
        int kt = k >> 4, m16 = k & 15;
        int step = v >> 5, q8 = (v >> 3) & 3, j = v & 7;
        rb[((size_t)(kt * 216 + step) * 64 + q8 * 16 + m16) * 8 + j] = (_Float16)val;
    }
}

// ---------------------------------------------------------------------------
// k_head: scale + J + apf(fragment layout) + level-parallel FK + an16.
// One wave per n. Joint IDs are level-ordered; tree depth 9, <=5 joints
// (60 lanes) per level.
__global__ __launch_bounds__(64) void k_head(const float* __restrict__ pose,
                                             const float* __restrict__ betas,
                                             const float* __restrict__ vt,
                                             const float* __restrict__ sd,
                                             float* __restrict__ ws,
                                             unsigned short* __restrict__ apf,
                                             _Float16* __restrict__ an16) {
    int n = blockIdx.x;
    int tid = threadIdx.x;
    __shared__ float sval[4];
    __shared__ float Jl[NJ * 3];
    __shared__ float G[NJ * 12];
    __shared__ unsigned short pfsh[KP];

    const int idx4[4] = {2802 * 3 + 1, 6262 * 3 + 1, 2237 * 3 + 1, 6728 * 3 + 1};
    if (tid < 4) {
        float a = vt[idx4[tid]];
#pragma unroll
        for (int k = 0; k < NB; ++k)
            a += betas[n * NB + k] * sd[(size_t)k * V3 + idx4[tid]];
        sval[tid] = a;
    }
    __syncthreads();
    float scale = 1.66f / (sval[0] + sval[1] - sval[2] - sval[3]);
    if (tid == 0) ws[SCALE_OFF + n] = scale;

    for (int k = tid; k < KP; k += 64) {
        float v = 0.f;
        if (k < NP) {
            v = pose[(size_t)n * 216 + 9 + k];
            int km = k % 9;
            if (km == 0 || km == 4 || km == 8) v -= 1.f;
        } else if (k < NP + NB) {
            v = scale * betas[n * NB + (k - NP)];
        }
        pfsh[k] = f2bf(v);
    }
    for (int e = tid; e < 72; e += 64) {
        float a = ws[JT_OFF + e];
#pragma unroll
        for (int k = 0; k < NB; ++k)
            a += betas[n * NB + k] * ws[SJ_OFF + (size_t)k * 72 + e];
        Jl[e] = scale * a;
    }
    __syncthreads();
    // apf fragment layout: [(n/16)*7+kk][lane=q*16+(n&15)][8]
    if (tid < 28) {
        int kk = tid >> 2, q = tid & 3;
        s16x8 r;
#pragma unroll
        for (int j = 0; j < 8; ++j) r[j] = (short)pfsh[kk * 32 + q * 8 + j];
        size_t off = ((size_t)(n >> 4) * 7 + kk) * 64 + q * 16 + (n & 15);
        *reinterpret_cast<s16x8*>(&apf[off * 8]) = r;
    }

    const int par[NJ] = {0,0,0,0,1,2,3,4,5,6,7,8,9,9,9,12,13,14,16,17,18,19,20,21};
    const int LV_OFF[10] = {0, 1, 4, 7, 10, 15, 18, 20, 22, 24};
    if (tid < 12) {
        int r = tid >> 2, c = tid & 3;
        G[tid] = (c < 3) ? pose[(size_t)n * 216 + r * 3 + c] : Jl[r];
    }
    __syncthreads();
#pragma unroll
    for (int l = 1; l <= 8; ++l) {
        int base = LV_OFF[l], cnt = LV_OFF[l + 1] - base;
        int jj = tid / 12, rc = tid - jj * 12;
        if (jj < cnt) {
            int i = base + jj;
            int p = par[i];
            int r = rc >> 2, c = rc & 3;
            const float* gp = &G[p * 12 + r * 4];
            float v;
            if (c < 3) {
                const float* Ri = pose + (size_t)n * 216 + i * 9;
                v = gp[0] * Ri[0 * 3 + c] + gp[1] * Ri[1 * 3 + c] + gp[2] * Ri[2 * 3 + c];
            } else {
                float t0 = Jl[i * 3 + 0] - Jl[p * 3 + 0];
                float t1 = Jl[i * 3 + 1] - Jl[p * 3 + 1];
                float t2 = Jl[i * 3 + 2] - Jl[p * 3 + 2];
                v = gp[0] * t0 + gp[1] * t1 + gp[2] * t2 + gp[3];
            }
            G[i * 12 + rc] = v;
        }
        __syncthreads();
    }
    // an16[n][col(16)][k=j(32)]
    for (int e = tid; e < 512; e += 64) {
        int col = e >> 5, j = e & 31;
        float v = 0.f;
        if (col < 12 && j < NJ) {
            int r = col >> 2, c = col & 3;
            if (c < 3) v = G[j * 12 + r * 4 + c];
            else {
                const float* g = &G[j * 12 + r * 4];
                v = g[3] - (g[0] * Jl[j * 3 + 0] + g[1] * Jl[j * 3 + 1] + g[2] * Jl[j * 3 + 2]);
            }
        }
        an16[(size_t)n * 512 + e] = (_Float16)v;
    }
}

// ---------------------------------------------------------------------------
// k_gl: fused pose-GEMM + LBS, 32v x 32n tiles, grid (216,16). Wave w:
// wg=w&1 picks 16-n group, wc=w>>1 picks 48-col half (3 ct x 7 kk MFMAs).
// Stage 2: wave w owns 8 n-rows x 32 verts via 2 register w16 frags
// (operand-swapped T-MFMA: lane (m,q) gets T[q][0..3] of vertex g*16+m).
// vb written in k_regm B-fragment layout (vstep == cb for 32-v tiles).
// 2 barriers total.
__global__ __launch_bounds__(256) void k_gl(const unsigned short* __restrict__ apf,
                                            const unsigned short* __restrict__ bp,
                                            const float* __restrict__ vt,
                                            const float* __restrict__ ws,
                                            const _Float16* __restrict__ w16,
                                            const _Float16* __restrict__ an16,
                                            const float* __restrict__ trans,
                                            _Float16* __restrict__ vb) {
    int tid = threadIdx.x;
    int lane = tid & 63, w = tid >> 6;
    int m = lane & 15, q = lane >> 4;
    int cb = blockIdx.x;                 // 0..215  (32-v tile)
    int nb = blockIdx.y;                 // 0..15   (32-n tile)
    int wg = w & 1;                      // n 16-group within tile
    int wc = w >> 1;                     // col 48-half

    // posed verts [n(32)][v(33 pad)][c(4)] fp16 = 8.25 KB; row stride 264 B.
    __shared__ __align__(16) _Float16 sm[32][33][4];
    __shared__ float svt[96];
    __shared__ float ssc[32];
    __shared__ float strans[96];
    if (tid < 96) {
        int col = cb * 96 + tid;
        svt[tid] = (col < V3) ? vt[col] : 0.f;
        strans[tid] = trans[nb * 96 + tid];
    }
    if (tid < 32) ssc[tid] = ws[SCALE_OFF + nb * 32 + tid];

    // ---- stage 1: pose GEMM (16 n x 48 cols per wave)
    const unsigned short* abase = apf + (size_t)(nb * 2 + wg) * 7 * 512 + lane * 8;
    const unsigned short* bbase = bp + (size_t)(cb * 6 + wc * 3) * 7 * 512 + lane * 8;

    f32x4 acc[3];
#pragma unroll
    for (int ct = 0; ct < 3; ++ct) acc[ct] = (f32x4){0.f, 0.f, 0.f, 0.f};

#pragma unroll
    for (int kk = 0; kk < 7; ++kk) {
        s16x8 a = *reinterpret_cast<const s16x8*>(abase + kk * 512);
#pragma unroll
        for (int ct = 0; ct < 3; ++ct) {
            s16x8 bfr = *reinterpret_cast<const s16x8*>(bbase + (ct * 7 + kk) * 512);
            acc[ct] = __builtin_amdgcn_mfma_f32_16x16x32_bf16(a, bfr, acc[ct], 0, 0, 0);
        }
    }

    // w16 fragments for the 2 vertex groups (independent of acc; issue early)
    h16x8 wf[2];
#pragma unroll
    for (int g = 0; g < 2; ++g)
        wf[g] = *reinterpret_cast<const h16x8*>(
            &w16[(size_t)(cb * 32 + g * 16 + m) * 32 + q * 8]);

    __syncthreads();          // svt/ssc/strans ready
#pragma unroll
    for (int ct = 0; ct < 3; ++ct) {
        int col_loc = (wc * 3 + ct) * 16 + m;
        int v_loc = col_loc / 3;
        int c = col_loc - 3 * v_loc;
        float vtc = svt[col_loc];
#pragma unroll
        for (int r = 0; r < 4; ++r) {
            int n_loc = wg * 16 + q * 4 + r;
            sm[n_loc][v_loc][c] = (_Float16)(acc[ct][r] + ssc[n_loc] * vtc);
        }
    }

    // ---- stage 2: LBS, wave w owns n-rows [w*8, w*8+8) x all 32 verts
    __syncthreads();                          // sm complete

    const _Float16* anb = an16 + (size_t)(nb * 32 + w * 8) * 512 + m * 32 + q * 8;
    // vb fragment write geometry (per lane, q<3):
    //   nc = n*3+q, v = cb*32 + g*16 + m (vstep == cb, q8 = g*2+(m>>3), j = m&7)
    //   addr = ((nc>>4)*216 + cb)*512 + (g*2+(m>>3))*128 + (nc&15)*8 + (m&7)
    int vsub = (m >> 3) * 128 + (m & 7);      // lane-constant part of q8/j
#pragma unroll
    for (int half = 0; half < 2; ++half) {
        h16x8 bf8[4];
#pragma unroll
        for (int i = 0; i < 4; ++i)
            bf8[i] = *reinterpret_cast<const h16x8*>(anb + (size_t)(half * 4 + i) * 512);
#pragma unroll
        for (int i = 0; i < 4; ++i) {
            int nl = w * 8 + half * 4 + i;
            f32x4 at[2];
#pragma unroll
            for (int g = 0; g < 2; ++g) {
                f32x4 z = (f32x4){0.f, 0.f, 0.f, 0.f};
                at[g] = __builtin_amdgcn_mfma_f32_16x16x32_f16(bf8[i], wf[g], z, 0, 0, 0);
            }
            if (q < 3) {
                float tr = strans[nl * 3 + q];
                int nc = (nb * 32 + nl) * 3 + q;
                size_t nbase = ((size_t)(nc >> 4) * 216 + cb) * 512 + (nc & 15) * 8;
#pragma unroll
                for (int g = 0; g < 2; ++g) {
                    int vl = g * 16 + m;
                    h16x4 p = *reinterpret_cast<const h16x4*>(&sm[nl][vl][0]);
                    float r = at[g][0] * (float)p[0] + at[g][1] * (float)p[1]
                            + at[g][2] * (float)p[2] + at[g][3] + tr;
                    vb[nbase + g * 256 + vsub] = (_Float16)r;
                }
            }
        }
    }
}

// ---------------------------------------------------------------------------
// k_regm: grid (96 nc-tiles x 6 v-splits) = 576 blocks, 4 waves, 9 K-steps.
// rb AND vb both in fragment layout: every operand load is a contiguous
// 1KB wave-load (4 cache lines). LDS combine across 4 waves, atomicAdd.
__global__ __launch_bounds__(256) void k_regm(const _Float16* __restrict__ rb,
                                              const _Float16* __restrict__ vb,
                                              float* __restrict__ out) {
    int tid = threadIdx.x;
    int lane = tid & 63, w = tid >> 6;
    int m = lane & 15, q = lane >> 4;
    int nct = blockIdx.x;                    // 0..95
    int split = blockIdx.y;                  // 0..5

    const _Float16* bbase = vb + (size_t)nct * 216 * 512 + (size_t)lane * 8;
    const _Float16* abase = rb + (size_t)lane * 8;
    int stepBase = (split * 4 + w) * 9;      // 9 steps of 32 per wave

    f32x4 acc[6];
#pragma unroll
    for (int kt = 0; kt < 6; ++kt) acc[kt] = (f32x4){0.f, 0.f, 0.f, 0.f};

#pragma unroll
    for (int s = 0; s < 9; ++s) {
        h16x8 b = *reinterpret_cast<const h16x8*>(
            bbase + (size_t)(stepBase + s) * 512);
#pragma unroll
        for (int kt = 0; kt < 6; ++kt) {
            h16x8 a = *reinterpret_cast<const h16x8*>(
                abase + ((size_t)(kt * 216 + stepBase + s) << 9));
            acc[kt] = __builtin_amdgcn_mfma_f32_16x16x32_f16(a, b, acc[kt], 0, 0, 0);
        }
    }
    __shared__ float sm[4][6][256];          // 24 KB
#pragma unroll
    for (int kt = 0; kt < 6; ++kt)
#pragma unroll
        for (int r = 0; r < 4; ++r)
            sm[w][kt][(q * 4 + r) * 16 + m] = acc[kt][r];
    __syncthreads();
    for (int e = tid; e < 6 * 256; e += 256) {
        int kt = e >> 8, i = e & 255;
        float s = sm[0][kt][i] + sm[1][kt][i] + sm[2][kt][i] + sm[3][kt][i];
        int k = kt * 16 + (i >> 4);
        int nc = nct * 16 + (i & 15);
        if (k < NK) {
            int n = nc / 3, c = nc - n * 3;
            atomicAdd(&out[(size_t)n * (NK * 3) + k * 3 + c], s);
        }
    }
}

// ---------------------------------------------------------------------------
extern "C" void kernel_launch(void* const* d_in, const int* in_sizes, int n_in,
                              void* d_out, int out_size, void* d_ws, size_t ws_size,
                              hipStream_t stream) {
    const float* pose  = (const float*)d_in[0];
    const float* betas = (const float*)d_in[1];
    const float* trans = (const float*)d_in[2];
    const float* vt    = (const float*)d_in[3];
    const float* sd    = (const float*)d_in[4];
    const float* jreg  = (const float*)d_in[5];
    const float* pdirs = (const float*)d_in[6];
    const float* lbsw  = (const float*)d_in[7];
    const float* b25   = (const float*)d_in[8];
    const float* face  = (const float*)d_in[9];
    float* ws  = (float*)d_ws;
    float* out = (float*)d_out;
    unsigned short* bf  = (unsigned short*)(ws + BF_OFF);
    unsigned short* apf = bf + APF_U;
    unsigned short* bp  = bf + BP_U;
    _Float16* rb  = (_Float16*)(bf + RB_U);
    _Float16* vb  = (_Float16*)(bf + VB_U);
    _Float16* w16 = (_Float16*)(ws + WT_OFF);
    _Float16* an16 = (_Float16*)(ws + AN_OFF);

    k_static<<<NB_STATIC, 256, 0, stream>>>(pdirs, sd, jreg, vt, lbsw, b25, face,
                                            bp, rb, w16, ws, out);
    k_head  <<<N, 64, 0, stream>>>(pose, betas, vt, sd, ws, apf, an16);
    k_gl    <<<dim3(216, 16), 256, 0, stream>>>(apf, bp, vt, ws, w16, an16, trans, vb);
    k_regm  <<<dim3(96, 6), 256, 0, stream>>>(rb, vb, out);
}